// Round 7
// baseline (9892.500 us; speedup 1.0000x reference)
//
#include <hip/hip_runtime.h>

typedef _Float16 half8 __attribute__((ext_vector_type(8)));
typedef float f32x4 __attribute__((ext_vector_type(4)));
typedef float f32x2 __attribute__((ext_vector_type(2)));
typedef unsigned uint4v __attribute__((ext_vector_type(4)));

#define BB 64
#define SS 512
#define DD 512
#define HH 1024
#define KK 1536
#define PKU4 12288           // packets per parity buffer: 64 rows * 64 producers * 3

#define MFMA(a, b, c) __builtin_amdgcn_mfma_f32_16x16x32_f16(a, b, c, 0, 0, 0)

// x-region fragment permutation (h-region is identity on both operands; the
// shared permutation cancels inside the MFMA dot product).
__device__ __host__ __forceinline__ int kperm(int k) {
  int blk = k >> 5, r = k & 31;
  return (blk << 5) | (((r >> 2) & 3) << 3) | ((r >> 4) << 2) | (r & 3);
}

// Pack weights: Wp[p][k'] fp16, p = b*80 + tile*16 + c  (tile: 0=g,1=r,2=z,3=i_n,4=h_n)
__global__ void prep_w(const float* __restrict__ Wg, const float* __restrict__ Wih,
                       const float* __restrict__ Whh, _Float16* __restrict__ Wp) {
  int p = blockIdx.x;
  int b = p / 80, rem = p % 80, t = rem >> 4, c = rem & 15;
  int j = b * 16 + c;
  for (int pass = 0; pass < 6; ++pass) {
    int k = pass * 256 + threadIdx.x;
    float v;
    if (t == 0)      v = Wg[k * HH + j];
    else if (t == 1) v = (k < DD) ? Wih[k * 3 * HH + j]          : Whh[(k - DD) * 3 * HH + j];
    else if (t == 2) v = (k < DD) ? Wih[k * 3 * HH + HH + j]     : Whh[(k - DD) * 3 * HH + HH + j];
    else if (t == 3) v = (k < DD) ? Wih[k * 3 * HH + 2 * HH + j] : 0.f;
    else             v = (k < DD) ? 0.f : Whh[(k - DD) * 3 * HH + 2 * HH + j];
    int pos = (k < DD) ? kperm(k) : k;      // x: kperm'd, h: identity
    Wp[(size_t)p * KK + pos] = (_Float16)v;
  }
}

// Xh[t][sg][row][lkg][8]: fp16 x in fragment-ready order (sg = x k-step 0..15)
__global__ void prep_xh(const float* __restrict__ x, _Float16* __restrict__ Xh) {
  int t = blockIdx.x, sg = blockIdx.y;
  int row = threadIdx.x >> 2, lkg = threadIdx.x & 3;
  const float* xp = x + ((size_t)row * SS + t) * DD + sg * 32 + lkg * 4;
  half8 hv;
#pragma unroll
  for (int j = 0; j < 4; ++j) { hv[j] = (_Float16)xp[j]; hv[4 + j] = (_Float16)xp[16 + j]; }
  *(half8*)(Xh + ((((size_t)t * 16 + sg) * 64 + row) * 4 + lkg) * 8) = hv;
}

// ---- packet layout --------------------------------------------------------
// Packet (row, producer p, s) at uint4 index (row*64+p)*3+s, 16B each:
//   s=0: h[row][16p+0..5] | s=1: h[row][16p+6..11] | s=2: h[row][16p+12..15],0,0
//   dword3 = tag (the step whose h this is). Fragment = 8 cols starting at
//   col0 = 16p + (lkg&1)*8; even lkg reads (s0,s1), odd reads (s1,s2).

__device__ __forceinline__ void issue_pk(const uint4v* __restrict__ Pb, int p, int s0,
                                         int lrow, uint4v (&P0)[4], uint4v (&P1)[4]) {
#pragma unroll
  for (int mt = 0; mt < 4; ++mt) {
    const uint4v* ap = Pb + ((size_t)((mt * 16 + lrow) * 64 + p) * 3 + s0);
    asm volatile("global_load_dwordx4 %0, %2, off sc0 sc1\n\t"
                 "global_load_dwordx4 %1, %2, off offset:16 sc0 sc1"
                 : "=&v"(P0[mt]), "=&v"(P1[mt]) : "v"(ap) : "memory");
  }
}

__device__ __forceinline__ int tags_ok(const uint4v (&P0)[4], const uint4v (&P1)[4],
                                       unsigned want) {
  unsigned bad = 0;
#pragma unroll
  for (int f = 0; f < 4; ++f) bad |= (P0[f][3] ^ want) | (P1[f][3] ^ want);
  return __all(bad == 0);
}

__device__ __forceinline__ void compute_pk(const uint4v (&P0)[4], const uint4v (&P1)[4],
                                           int odd, int kb, const half8 (&bh)[3][4],
                                           const half8 (&b4)[4], f32x4 (&acc)[5][4]) {
#pragma unroll
  for (int mt = 0; mt < 4; ++mt) {
    uint4v fv;
    fv[0] = odd ? P0[mt][1] : P0[mt][0];
    fv[1] = odd ? P0[mt][2] : P0[mt][1];
    fv[2] = odd ? P1[mt][0] : P0[mt][2];
    fv[3] = odd ? P1[mt][1] : P1[mt][0];
    half8 af = __builtin_bit_cast(half8, fv);
    acc[0][mt] = MFMA(af, bh[0][kb], acc[0][mt]);
    acc[1][mt] = MFMA(af, bh[1][kb], acc[1][mt]);
    acc[2][mt] = MFMA(af, bh[2][kb], acc[2][mt]);
    acc[4][mt] = MFMA(af, b4[kb], acc[4][mt]);
  }
}

#define WAITV(lit) do { asm volatile("s_waitcnt vmcnt(" lit ")" ::: "memory"); \
                        __builtin_amdgcn_sched_barrier(0); } while (0)
// Retry path (rare): reissue just this batch, full drain, recheck.
#define RETRY(P0a, P1a, p, s0) do { \
    if (!tags_ok(P0a, P1a, want)) { \
      do { issue_pk(Pb, p, s0, lrow, P0a, P1a); WAITV("0"); } \
      while (!tags_ok(P0a, P1a, want)); } } while (0)

__global__ __launch_bounds__(512, 2) void rnn_seq(
    const _Float16* __restrict__ Xh, const _Float16* __restrict__ Wp,
    const float* __restrict__ bg, const float* __restrict__ bih,
    const float* __restrict__ bhh, float* __restrict__ out,
    uint4v* __restrict__ Pk, uint4v* __restrict__ sink) {
  const int blk = blockIdx.x;
  const int tid = threadIdx.x;
  const int w = tid >> 6;              // wave 0..7
  const int lane = tid & 63;
  const int lrow = lane & 15;
  const int lkg = lane >> 4;
  const int odd = lkg & 1;
  const int s0 = lkg & 1;

  __shared__ float Red[4][80][68];               // 87,040 B
  __shared__ alignas(16) _Float16 Hst[64][16];   //  2,048 B
  __shared__ alignas(16) _Float16 Xstage[64 * 512];  // 65,536 B

  const int ej = tid & 15;
  const int rpp = tid >> 4;            // 0..31
  const int ghcol = blk * 16 + ej;
  const float bg_b  = bg[ghcol];
  const float br_b  = bih[ghcol] + bhh[ghcol];
  const float bz_b  = bih[HH + ghcol] + bhh[HH + ghcol];
  const float bin_b = bih[2 * HH + ghcol];
  const float bhn_b = bhh[2 * HH + ghcol];
  float hreg[2] = {0.f, 0.f};

  // producer index per (wave, kb): h-cols [(w*4+kb)*32 + lkg*8 ...+8)
  // -> p = (w*4+kb)*2 + (lkg>>1)
  const int pbase = w * 8 + (lkg >> 1);          // p = pbase + kb*2

  // register-resident weights (24 half8 = 96 VGPR), round-5 layout
  half8 bx[3][2], b3[2], bh[3][4], b4[4];
#pragma unroll
  for (int tt = 0; tt < 3; ++tt)
#pragma unroll
    for (int kk = 0; kk < 2; ++kk)
      bx[tt][kk] = *(const half8*)(Wp + (size_t)(blk * 80 + tt * 16 + lrow) * KK + (w * 2 + kk) * 32 + lkg * 8);
#pragma unroll
  for (int kk = 0; kk < 2; ++kk)
    b3[kk] = *(const half8*)(Wp + (size_t)(blk * 80 + 48 + lrow) * KK + (w * 2 + kk) * 32 + lkg * 8);
#pragma unroll
  for (int tt = 0; tt < 3; ++tt)
#pragma unroll
    for (int kk = 0; kk < 4; ++kk)
      bh[tt][kk] = *(const half8*)(Wp + (size_t)(blk * 80 + tt * 16 + lrow) * KK + (16 + w * 4 + kk) * 32 + lkg * 8);
#pragma unroll
  for (int kk = 0; kk < 4; ++kk)
    b4[kk] = *(const half8*)(Wp + (size_t)(blk * 80 + 64 + lrow) * KK + (16 + w * 4 + kk) * 32 + lkg * 8);

  // prefetch Xstage(t=0): 8 chunks per wave (kk 0..1, mt 0..3)
#pragma unroll
  for (int kk = 0; kk < 2; ++kk)
#pragma unroll
    for (int mt = 0; mt < 4; ++mt) {
      const _Float16* gsrc = Xh + ((((size_t)0 * 16 + (w * 2 + kk)) * 64 + (mt * 16 + lrow)) * 4 + lkg) * 8;
      __builtin_amdgcn_global_load_lds(
          (const __attribute__((address_space(1))) void*)gsrc,
          (__attribute__((address_space(3))) void*)(Xstage + (w * 8 + kk * 4 + mt) * 512), 16, 0, 0);
    }
  WAITV("0");

  for (int t = 0; t < SS; ++t) {
    const uint4v* Pb = Pk + (size_t)(t & 1) * PKU4;
    uint4v* Pn = Pk + (size_t)((t + 1) & 1) * PKU4;
    const unsigned want = (unsigned)t;

    f32x4 zz = {0.f, 0.f, 0.f, 0.f};
    f32x4 acc[5][4];
#pragma unroll
    for (int tt = 0; tt < 5; ++tt)
#pragma unroll
      for (int mt = 0; mt < 4; ++mt) acc[tt][mt] = zz;

    // issue kk0, kk1 packet batches first — RT overlaps the x-phase.
    // VMEM queue (in order): [S:1 pub store (t>0)][E:8][F:8][xpref:8][G:8][H:8]
    uint4v E0[4], E1[4], F0[4], F1[4];
    issue_pk(Pb, pbase + 0, s0, lrow, E0, E1);
    issue_pk(Pb, pbase + 2, s0, lrow, F0, F1);

    // ---- x-part from LDS (DS-only) ----
#pragma unroll
    for (int kk = 0; kk < 2; ++kk) {
      half8 afr[4];
#pragma unroll
      for (int mt = 0; mt < 4; ++mt)
        afr[mt] = *(const half8*)(Xstage + (w * 8 + kk * 4 + mt) * 512 + lane * 8);
#pragma unroll
      for (int mt = 0; mt < 4; ++mt) {
        acc[0][mt] = MFMA(afr[mt], bx[0][kk], acc[0][mt]);
        acc[1][mt] = MFMA(afr[mt], bx[1][kk], acc[1][mt]);
        acc[2][mt] = MFMA(afr[mt], bx[2][kk], acc[2][mt]);
        acc[3][mt] = MFMA(afr[mt], b3[kk], acc[3][mt]);
      }
    }

    // xpref(t+1): after x ds_reads retire (WAR; Xstage chunks are wave-private)
    {
      const int tn = (t + 1 < SS) ? t + 1 : t;
      asm volatile("s_waitcnt lgkmcnt(0)" ::: "memory");
      __builtin_amdgcn_sched_barrier(0);
#pragma unroll
      for (int kk = 0; kk < 2; ++kk)
#pragma unroll
        for (int mt = 0; mt < 4; ++mt) {
          const _Float16* gsrc = Xh + ((((size_t)tn * 16 + (w * 2 + kk)) * 64 + (mt * 16 + lrow)) * 4 + lkg) * 8;
          __builtin_amdgcn_global_load_lds(
              (const __attribute__((address_space(1))) void*)gsrc,
              (__attribute__((address_space(3))) void*)(Xstage + (w * 8 + kk * 4 + mt) * 512), 16, 0, 0);
        }
    }

    // ---- h-phase: counted waits; constants = #VMEM ops issued after target
    WAITV("16");                                   // E done (F:8 + xpref:8 behind it)
    RETRY(E0, E1, pbase + 0, s0);
    compute_pk(E0, E1, odd, 0, bh, b4, acc);
    issue_pk(Pb, pbase + 4, s0, lrow, E0, E1);     // kk2 -> E
    WAITV("16");                                   // F done (xpref:8 + kk2:8 behind)
    RETRY(F0, F1, pbase + 2, s0);
    compute_pk(F0, F1, odd, 1, bh, b4, acc);
    issue_pk(Pb, pbase + 6, s0, lrow, F0, F1);     // kk3 -> F
    WAITV("8");                                    // kk2 done (kk3:8 behind; xpref forced too)
    RETRY(E0, E1, pbase + 4, s0);
    compute_pk(E0, E1, odd, 2, bh, b4, acc);
    WAITV("0");                                    // kk3 done
    RETRY(F0, F1, pbase + 6, s0);
    compute_pk(F0, F1, odd, 3, bh, b4, acc);

    // ---- cross-wave reduction (8 partials -> 4), round-5 exact ----
    if (w >= 4) {
#pragma unroll
      for (int tt = 0; tt < 5; ++tt)
#pragma unroll
        for (int mt = 0; mt < 4; ++mt)
          *(f32x4*)&Red[w - 4][tt * 16 + lrow][mt * 16 + lkg * 4] = acc[tt][mt];
    }
    __syncthreads();
    if (w < 4) {
#pragma unroll
      for (int tt = 0; tt < 5; ++tt)
#pragma unroll
        for (int mt = 0; mt < 4; ++mt) {
          f32x4* p = (f32x4*)&Red[w][tt * 16 + lrow][mt * 16 + lkg * 4];
          *p = *p + acc[tt][mt];
        }
    }
    __syncthreads();

    // ---- epilogue: all 512 threads, 2 rows x 1 col ----
    {
      f32x2 s[5];
#pragma unroll
      for (int g = 0; g < 5; ++g) {
        f32x2 a = *(const f32x2*)&Red[0][g * 16 + ej][rpp * 2];
#pragma unroll
        for (int ww = 1; ww < 4; ++ww)
          a = a + *(const f32x2*)&Red[ww][g * 16 + ej][rpp * 2];
        s[g] = a;
      }
#pragma unroll
      for (int r = 0; r < 2; ++r) {
        float g_ = 1.f / (1.f + __expf(-(s[0][r] + bg_b)));
        float r_ = 1.f / (1.f + __expf(-(s[1][r] + br_b)));
        float z_ = 1.f / (1.f + __expf(-(s[2][r] + bz_b)));
        float n_ = tanhf(s[3][r] + bin_b + r_ * (s[4][r] + bhn_b));
        float h = g_ * ((1.f - z_) * n_ + z_ * hreg[r]);
        hreg[r] = h;
        int row = rpp * 2 + r;
        if (t == SS - 1) out[row * HH + ghcol] = h;
        else             Hst[row][ej] = (_Float16)h;
      }
    }

    // ---- publish: fire-and-forget tagged packets; no drain, no flag ----
    if (t < SS - 1) {
      __syncthreads();                 // Hst complete (also fences Red reads vs next writes)
      uint4v pk = {0u, 0u, 0u, (unsigned)(t + 1)};
      uint4v* dst = sink + (size_t)blk * 512 + tid;
      if (tid < 256) {
        const int prow = tid >> 2, ps = tid & 3;
        uint4v lo = *(const uint4v*)&Hst[prow][0];
        uint4v hi = *(const uint4v*)&Hst[prow][8];
        if (ps == 0)      { pk[0] = lo[0]; pk[1] = lo[1]; pk[2] = lo[2]; }
        else if (ps == 1) { pk[0] = lo[3]; pk[1] = hi[0]; pk[2] = hi[1]; }
        else if (ps == 2) { pk[0] = hi[2]; pk[1] = hi[3]; }
        if (ps < 3) dst = Pn + ((size_t)(prow * 64 + blk) * 3 + ps);
      }
      // exactly ONE store per thread -> uniform per-wave vmcnt accounting
      asm volatile("global_store_dwordx4 %0, %1, off sc0 sc1" :: "v"(dst), "v"(pk) : "memory");
    }
  }
}

extern "C" void kernel_launch(void* const* d_in, const int* in_sizes, int n_in,
                              void* d_out, int out_size, void* d_ws, size_t ws_size,
                              hipStream_t stream) {
  const float* x   = (const float*)d_in[0];
  const float* Wg  = (const float*)d_in[1];
  const float* bg  = (const float*)d_in[2];
  const float* Wih = (const float*)d_in[3];
  const float* bih = (const float*)d_in[4];
  const float* Whh = (const float*)d_in[5];
  const float* bhh = (const float*)d_in[6];
  // d_in[7..10] (Wa, ba, Ws, bs) are mathematically dead: softmax over size-1 axis == 1
  float* out = (float*)d_out;

  char* ws = (char*)d_ws;
  _Float16* Wp   = (_Float16*)ws;                        // 15,728,640 B
  _Float16* Xh   = (_Float16*)(ws + 15728640);           // 33,554,432 B
  uint4v*   Pk   = (uint4v*)(ws + 15728640 + 33554432);  // 2*196,608 = 393,216 B
  uint4v*   sink = (uint4v*)(ws + 15728640 + 33554432 + 393216);  // 524,288 B

  hipMemsetAsync((void*)Pk, 0, 393216, stream);          // tag 0 == h(0) = 0
  prep_w<<<5120, 256, 0, stream>>>(Wg, Wih, Whh, Wp);
  prep_xh<<<dim3(512, 16), 256, 0, stream>>>(x, Xh);
  rnn_seq<<<64, 512, 0, stream>>>(Xh, Wp, bg, bih, bhh, out, Pk, sink);
}

// Round 8
// 9702.884 us; speedup vs baseline: 1.0195x; 1.0195x over previous
//
#include <hip/hip_runtime.h>

typedef _Float16 half8 __attribute__((ext_vector_type(8)));
typedef float f32x4 __attribute__((ext_vector_type(4)));
typedef float f32x2 __attribute__((ext_vector_type(2)));
typedef unsigned uint4v __attribute__((ext_vector_type(4)));

#define BB 64
#define SS 512
#define DD 512
#define HH 1024
#define KK 1536
#define PKU4 12288           // packets per parity buffer: 64 rows * 64 producers * 3

#define MFMA(a, b, c) __builtin_amdgcn_mfma_f32_16x16x32_f16(a, b, c, 0, 0, 0)

// x-region fragment permutation (h-region is identity on both operands; the
// shared permutation cancels inside the MFMA dot product).
__device__ __host__ __forceinline__ int kperm(int k) {
  int blk = k >> 5, r = k & 31;
  return (blk << 5) | (((r >> 2) & 3) << 3) | ((r >> 4) << 2) | (r & 3);
}

// Pack weights: Wp[p][k'] fp16, p = b*80 + tile*16 + c  (tile: 0=g,1=r,2=z,3=i_n,4=h_n)
__global__ void prep_w(const float* __restrict__ Wg, const float* __restrict__ Wih,
                       const float* __restrict__ Whh, _Float16* __restrict__ Wp) {
  int p = blockIdx.x;
  int b = p / 80, rem = p % 80, t = rem >> 4, c = rem & 15;
  int j = b * 16 + c;
  for (int pass = 0; pass < 6; ++pass) {
    int k = pass * 256 + threadIdx.x;
    float v;
    if (t == 0)      v = Wg[k * HH + j];
    else if (t == 1) v = (k < DD) ? Wih[k * 3 * HH + j]          : Whh[(k - DD) * 3 * HH + j];
    else if (t == 2) v = (k < DD) ? Wih[k * 3 * HH + HH + j]     : Whh[(k - DD) * 3 * HH + HH + j];
    else if (t == 3) v = (k < DD) ? Wih[k * 3 * HH + 2 * HH + j] : 0.f;
    else             v = (k < DD) ? 0.f : Whh[(k - DD) * 3 * HH + 2 * HH + j];
    int pos = (k < DD) ? kperm(k) : k;      // x: kperm'd, h: identity
    Wp[(size_t)p * KK + pos] = (_Float16)v;
  }
}

// Xh[t][sg][row][lkg][8]: fp16 x in fragment-ready order (sg = x k-step 0..15)
__global__ void prep_xh(const float* __restrict__ x, _Float16* __restrict__ Xh) {
  int t = blockIdx.x, sg = blockIdx.y;
  int row = threadIdx.x >> 2, lkg = threadIdx.x & 3;
  const float* xp = x + ((size_t)row * SS + t) * DD + sg * 32 + lkg * 4;
  half8 hv;
#pragma unroll
  for (int j = 0; j < 4; ++j) { hv[j] = (_Float16)xp[j]; hv[4 + j] = (_Float16)xp[16 + j]; }
  *(half8*)(Xh + ((((size_t)t * 16 + sg) * 64 + row) * 4 + lkg) * 8) = hv;
}

// ---- packet layout --------------------------------------------------------
// Packet (row, producer p, s) at uint4 index (row*64+p)*3+s, 16B each:
//   s=0: h[row][16p+0..5] | s=1: h[row][16p+6..11] | s=2: h[row][16p+12..15],0,0
//   dword3 = tag (the step whose h this is). Fragment = 8 cols starting at
//   col0 = 16p + (lkg&1)*8; even lkg reads (s0,s1), odd reads (s1,s2).
// 16B aligned stores are single-copy atomic at the coherent point (validated
// rounds 6-7), so tag-validity implies data-validity per packet.

__device__ __forceinline__ void issue_pk(const uint4v* __restrict__ Pb, int p, int s0,
                                         int lrow, uint4v (&P0)[4], uint4v (&P1)[4]) {
#pragma unroll
  for (int mt = 0; mt < 4; ++mt) {
    const uint4v* ap = Pb + ((size_t)((mt * 16 + lrow) * 64 + p) * 3 + s0);
    asm volatile("global_load_dwordx4 %0, %2, off sc0 sc1\n\t"
                 "global_load_dwordx4 %1, %2, off offset:16 sc0 sc1"
                 : "=&v"(P0[mt]), "=&v"(P1[mt]) : "v"(ap) : "memory");
  }
}

__device__ __forceinline__ int tags_ok(const uint4v (&P0)[4], const uint4v (&P1)[4],
                                       unsigned want) {
  unsigned bad = 0;
#pragma unroll
  for (int f = 0; f < 4; ++f) bad |= (P0[f][3] ^ want) | (P1[f][3] ^ want);
  return __all(bad == 0);
}

__device__ __forceinline__ void compute_pk(const uint4v (&P0)[4], const uint4v (&P1)[4],
                                           int odd, int kb, const half8 (&bh)[3][4],
                                           const half8 (&b4)[4], f32x4 (&acc)[5][4]) {
#pragma unroll
  for (int mt = 0; mt < 4; ++mt) {
    uint4v fv;
    fv[0] = odd ? P0[mt][1] : P0[mt][0];
    fv[1] = odd ? P0[mt][2] : P0[mt][1];
    fv[2] = odd ? P1[mt][0] : P0[mt][2];
    fv[3] = odd ? P1[mt][1] : P1[mt][0];
    half8 af = __builtin_bit_cast(half8, fv);
    acc[0][mt] = MFMA(af, bh[0][kb], acc[0][mt]);
    acc[1][mt] = MFMA(af, bh[1][kb], acc[1][mt]);
    acc[2][mt] = MFMA(af, bh[2][kb], acc[2][mt]);
    acc[4][mt] = MFMA(af, b4[kb], acc[4][mt]);
  }
}

#define WAITV(lit) do { asm volatile("s_waitcnt vmcnt(" lit ")" ::: "memory"); \
                        __builtin_amdgcn_sched_barrier(0); } while (0)

__global__ __launch_bounds__(512, 2) void rnn_seq(
    const _Float16* __restrict__ Xh, const _Float16* __restrict__ Wp,
    const float* __restrict__ bg, const float* __restrict__ bih,
    const float* __restrict__ bhh, float* __restrict__ out,
    uint4v* __restrict__ Pk, uint4v* __restrict__ sink) {
  const int blk = blockIdx.x;
  const int tid = threadIdx.x;
  const int w = tid >> 6;              // wave 0..7
  const int lane = tid & 63;
  const int lrow = lane & 15;
  const int lkg = lane >> 4;
  const int odd = lkg & 1;
  const int s0 = lkg & 1;

  __shared__ float Red[4][80][68];               // 87,040 B
  __shared__ alignas(16) _Float16 Hst[64][16];   //  2,048 B
  __shared__ alignas(16) _Float16 Xstage[64 * 512];  // 65,536 B

  const int ej = tid & 15;
  const int rpp = tid >> 4;            // 0..31
  const int ghcol = blk * 16 + ej;
  const float bg_b  = bg[ghcol];
  const float br_b  = bih[ghcol] + bhh[ghcol];
  const float bz_b  = bih[HH + ghcol] + bhh[HH + ghcol];
  const float bin_b = bih[2 * HH + ghcol];
  const float bhn_b = bhh[2 * HH + ghcol];
  float hreg[2] = {0.f, 0.f};

  // producer index: batch kb covers h-cols [(w*4+kb)*32 + lkg*8, +8)
  // -> producer p = pbase + kb*2, col offset within producer = (lkg&1)*8
  const int pbase = w * 8 + (lkg >> 1);

  // register-resident weights (24 half8 = 96 VGPR), round-5 layout
  half8 bx[3][2], b3[2], bh[3][4], b4[4];
#pragma unroll
  for (int tt = 0; tt < 3; ++tt)
#pragma unroll
    for (int kk = 0; kk < 2; ++kk)
      bx[tt][kk] = *(const half8*)(Wp + (size_t)(blk * 80 + tt * 16 + lrow) * KK + (w * 2 + kk) * 32 + lkg * 8);
#pragma unroll
  for (int kk = 0; kk < 2; ++kk)
    b3[kk] = *(const half8*)(Wp + (size_t)(blk * 80 + 48 + lrow) * KK + (w * 2 + kk) * 32 + lkg * 8);
#pragma unroll
  for (int tt = 0; tt < 3; ++tt)
#pragma unroll
    for (int kk = 0; kk < 4; ++kk)
      bh[tt][kk] = *(const half8*)(Wp + (size_t)(blk * 80 + tt * 16 + lrow) * KK + (16 + w * 4 + kk) * 32 + lkg * 8);
#pragma unroll
  for (int kk = 0; kk < 4; ++kk)
    b4[kk] = *(const half8*)(Wp + (size_t)(blk * 80 + 64 + lrow) * KK + (16 + w * 4 + kk) * 32 + lkg * 8);

  // prefetch Xstage(t=0)
#pragma unroll
  for (int kk = 0; kk < 2; ++kk)
#pragma unroll
    for (int mt = 0; mt < 4; ++mt) {
      const _Float16* gsrc = Xh + ((((size_t)0 * 16 + (w * 2 + kk)) * 64 + (mt * 16 + lrow)) * 4 + lkg) * 8;
      __builtin_amdgcn_global_load_lds(
          (const __attribute__((address_space(1))) void*)gsrc,
          (__attribute__((address_space(3))) void*)(Xstage + (w * 8 + kk * 4 + mt) * 512), 16, 0, 0);
    }
  WAITV("0");

  for (int t = 0; t < SS; ++t) {
    const uint4v* Pb = Pk + (size_t)(t & 1) * PKU4;
    uint4v* Pn = Pk + (size_t)((t + 1) & 1) * PKU4;
    const unsigned want = (unsigned)t;

    // loop-top: xpref(t) must be resident before x ds_reads. Queue per wave:
    // waves 0-3: [xpref:8][pub:1] -> vmcnt(1); waves 4-7: [xpref:8] -> vmcnt(0)
    if (t > 0) { if (w < 4) WAITV("1"); else WAITV("0"); }

    f32x4 zz = {0.f, 0.f, 0.f, 0.f};
    f32x4 acc[5][4];
#pragma unroll
    for (int tt = 0; tt < 5; ++tt)
#pragma unroll
      for (int mt = 0; mt < 4; ++mt) acc[tt][mt] = zz;

    // issue h batches A(kb0), B(kb1); their RT overlaps the x-phase. First tag
    // check happens post-x-phase, by when producers (who publish BEFORE their
    // own x-phase) have landed -> first check usually clean, retries rare.
    uint4v A0[4], A1[4], B0[4], B1[4];
    issue_pk(Pb, pbase + 0, s0, lrow, A0, A1);
    issue_pk(Pb, pbase + 2, s0, lrow, B0, B1);

    // ---- x-part from LDS (DS-only) ----
#pragma unroll
    for (int kk = 0; kk < 2; ++kk) {
      half8 afr[4];
#pragma unroll
      for (int mt = 0; mt < 4; ++mt)
        afr[mt] = *(const half8*)(Xstage + (w * 8 + kk * 4 + mt) * 512 + lane * 8);
#pragma unroll
      for (int mt = 0; mt < 4; ++mt) {
        acc[0][mt] = MFMA(afr[mt], bx[0][kk], acc[0][mt]);
        acc[1][mt] = MFMA(afr[mt], bx[1][kk], acc[1][mt]);
        acc[2][mt] = MFMA(afr[mt], bx[2][kk], acc[2][mt]);
        acc[3][mt] = MFMA(afr[mt], b3[kk], acc[3][mt]);
      }
    }

    // ---- sync1: collective check of A,B; reissue only stale batches.
    // Nothing else in the VMEM queue here -> vmcnt(0) waits only h data.
    for (;;) {
      WAITV("0");
      int okA = tags_ok(A0, A1, want);
      int okB = tags_ok(B0, B1, want);
      if (okA && okB) break;
      if (!okA) issue_pk(Pb, pbase + 0, s0, lrow, A0, A1);
      if (!okB) issue_pk(Pb, pbase + 2, s0, lrow, B0, B1);
    }
    compute_pk(A0, A1, odd, 0, bh, b4, acc);
    issue_pk(Pb, pbase + 4, s0, lrow, A0, A1);   // C -> A regs
    compute_pk(B0, B1, odd, 1, bh, b4, acc);
    issue_pk(Pb, pbase + 6, s0, lrow, B0, B1);   // D -> B regs

    // ---- sync2: C,D (data was published together with A,B -> ~1 clean RT)
    for (;;) {
      WAITV("0");
      int okC = tags_ok(A0, A1, want);
      int okD = tags_ok(B0, B1, want);
      if (okC && okD) break;
      if (!okC) issue_pk(Pb, pbase + 4, s0, lrow, A0, A1);
      if (!okD) issue_pk(Pb, pbase + 6, s0, lrow, B0, B1);
    }
    compute_pk(A0, A1, odd, 2, bh, b4, acc);
    compute_pk(B0, B1, odd, 3, bh, b4, acc);

    // ---- xpref(t+1): outside the retry window; drains by next loop-top ----
    if (t + 1 < SS) {
      asm volatile("s_waitcnt lgkmcnt(0)" ::: "memory");
      __builtin_amdgcn_sched_barrier(0);
#pragma unroll
      for (int kk = 0; kk < 2; ++kk)
#pragma unroll
        for (int mt = 0; mt < 4; ++mt) {
          const _Float16* gsrc = Xh + ((((size_t)(t + 1) * 16 + (w * 2 + kk)) * 64 + (mt * 16 + lrow)) * 4 + lkg) * 8;
          __builtin_amdgcn_global_load_lds(
              (const __attribute__((address_space(1))) void*)gsrc,
              (__attribute__((address_space(3))) void*)(Xstage + (w * 8 + kk * 4 + mt) * 512), 16, 0, 0);
        }
    }

    // ---- cross-wave reduction (8 partials -> 4) ----
    if (w >= 4) {
#pragma unroll
      for (int tt = 0; tt < 5; ++tt)
#pragma unroll
        for (int mt = 0; mt < 4; ++mt)
          *(f32x4*)&Red[w - 4][tt * 16 + lrow][mt * 16 + lkg * 4] = acc[tt][mt];
    }
    __syncthreads();
    if (w < 4) {
#pragma unroll
      for (int tt = 0; tt < 5; ++tt)
#pragma unroll
        for (int mt = 0; mt < 4; ++mt) {
          f32x4* p = (f32x4*)&Red[w][tt * 16 + lrow][mt * 16 + lkg * 4];
          *p = *p + acc[tt][mt];
        }
    }
    __syncthreads();

    // ---- epilogue: all 512 threads, 2 rows x 1 col ----
    {
      f32x2 s[5];
#pragma unroll
      for (int g = 0; g < 5; ++g) {
        f32x2 a = *(const f32x2*)&Red[0][g * 16 + ej][rpp * 2];
#pragma unroll
        for (int ww = 1; ww < 4; ++ww)
          a = a + *(const f32x2*)&Red[ww][g * 16 + ej][rpp * 2];
        s[g] = a;
      }
#pragma unroll
      for (int r = 0; r < 2; ++r) {
        float g_ = 1.f / (1.f + __expf(-(s[0][r] + bg_b)));
        float r_ = 1.f / (1.f + __expf(-(s[1][r] + br_b)));
        float z_ = 1.f / (1.f + __expf(-(s[2][r] + bz_b)));
        float n_ = tanhf(s[3][r] + bin_b + r_ * (s[4][r] + bhn_b));
        float h = g_ * ((1.f - z_) * n_ + z_ * hreg[r]);
        hreg[r] = h;
        int row = rpp * 2 + r;
        if (t == SS - 1) out[row * HH + ghcol] = h;
        else             Hst[row][ej] = (_Float16)h;
      }
    }

    // ---- publish: fire-and-forget tagged packets; NO drain, NO flag ----
    if (t < SS - 1) {
      __syncthreads();                 // Hst complete (also fences Red reads)
      if (tid < 256) {                 // waves 0-3: exactly 1 store each
        const int prow = tid >> 2, ps = tid & 3;
        uint4v lo = *(const uint4v*)&Hst[prow][0];
        uint4v hi = *(const uint4v*)&Hst[prow][8];
        uint4v pk = {0u, 0u, 0u, (unsigned)(t + 1)};
        uint4v* dst;
        if (ps == 0)      { pk[0] = lo[0]; pk[1] = lo[1]; pk[2] = lo[2]; }
        else if (ps == 1) { pk[0] = lo[3]; pk[1] = hi[0]; pk[2] = hi[1]; }
        else if (ps == 2) { pk[0] = hi[2]; pk[1] = hi[3]; }
        dst = (ps < 3) ? (Pn + ((size_t)(prow * 64 + blk) * 3 + ps))
                       : (sink + (size_t)blk * 256 + tid);
        asm volatile("global_store_dwordx4 %0, %1, off sc0 sc1" :: "v"(dst), "v"(pk) : "memory");
      }
    }
  }
}

extern "C" void kernel_launch(void* const* d_in, const int* in_sizes, int n_in,
                              void* d_out, int out_size, void* d_ws, size_t ws_size,
                              hipStream_t stream) {
  const float* x   = (const float*)d_in[0];
  const float* Wg  = (const float*)d_in[1];
  const float* bg  = (const float*)d_in[2];
  const float* Wih = (const float*)d_in[3];
  const float* bih = (const float*)d_in[4];
  const float* Whh = (const float*)d_in[5];
  const float* bhh = (const float*)d_in[6];
  // d_in[7..10] (Wa, ba, Ws, bs) are mathematically dead: softmax over size-1 axis == 1
  float* out = (float*)d_out;

  char* ws = (char*)d_ws;
  _Float16* Wp   = (_Float16*)ws;                        // 15,728,640 B
  _Float16* Xh   = (_Float16*)(ws + 15728640);           // 33,554,432 B
  uint4v*   Pk   = (uint4v*)(ws + 15728640 + 33554432);  // 2*196,608 = 393,216 B
  uint4v*   sink = (uint4v*)(ws + 15728640 + 33554432 + 393216);  // 524,288 B

  // Clear BOTH parities every launch: tags reset to 0 (= valid h0 for t=0;
  // never matches want=t>0, so leftovers from a previous replay can't alias).
  hipMemsetAsync((void*)Pk, 0, 393216, stream);
  prep_w<<<5120, 256, 0, stream>>>(Wg, Wih, Whh, Wp);
  prep_xh<<<dim3(512, 16), 256, 0, stream>>>(x, Xh);
  rnn_seq<<<64, 512, 0, stream>>>(Xh, Wp, bg, bih, bhh, out, Pk, sink);
}

// Round 9
// 6165.275 us; speedup vs baseline: 1.6046x; 1.5738x over previous
//
#include <hip/hip_runtime.h>

typedef _Float16 half8 __attribute__((ext_vector_type(8)));
typedef float f32x4 __attribute__((ext_vector_type(4)));
typedef float f32x2 __attribute__((ext_vector_type(2)));
typedef unsigned uint4v __attribute__((ext_vector_type(4)));

#define BB 64
#define SS 512
#define DD 512
#define HH 1024
#define KK 1536
#define PKU4 12288           // per parity: 64 producers * 64 rows * 3 packets

#define MFMA(a, b, c) __builtin_amdgcn_mfma_f32_16x16x32_f16(a, b, c, 0, 0, 0)

// x-region fragment permutation (h-region is identity on both operands; the
// shared permutation cancels inside the MFMA dot product).
__device__ __host__ __forceinline__ int kperm(int k) {
  int blk = k >> 5, r = k & 31;
  return (blk << 5) | (((r >> 2) & 3) << 3) | ((r >> 4) << 2) | (r & 3);
}

// Pack weights: Wp[p][k'] fp16, p = b*80 + tile*16 + c  (tile: 0=g,1=r,2=z,3=i_n,4=h_n)
__global__ void prep_w(const float* __restrict__ Wg, const float* __restrict__ Wih,
                       const float* __restrict__ Whh, _Float16* __restrict__ Wp) {
  int p = blockIdx.x;
  int b = p / 80, rem = p % 80, t = rem >> 4, c = rem & 15;
  int j = b * 16 + c;
  for (int pass = 0; pass < 6; ++pass) {
    int k = pass * 256 + threadIdx.x;
    float v;
    if (t == 0)      v = Wg[k * HH + j];
    else if (t == 1) v = (k < DD) ? Wih[k * 3 * HH + j]          : Whh[(k - DD) * 3 * HH + j];
    else if (t == 2) v = (k < DD) ? Wih[k * 3 * HH + HH + j]     : Whh[(k - DD) * 3 * HH + HH + j];
    else if (t == 3) v = (k < DD) ? Wih[k * 3 * HH + 2 * HH + j] : 0.f;
    else             v = (k < DD) ? 0.f : Whh[(k - DD) * 3 * HH + 2 * HH + j];
    int pos = (k < DD) ? kperm(k) : k;      // x: kperm'd, h: identity
    Wp[(size_t)p * KK + pos] = (_Float16)v;
  }
}

// Xh[t][sg][row][lkg][8]: fp16 x in fragment-ready order (sg = x k-step 0..15)
__global__ void prep_xh(const float* __restrict__ x, _Float16* __restrict__ Xh) {
  int t = blockIdx.x, sg = blockIdx.y;
  int row = threadIdx.x >> 2, lkg = threadIdx.x & 3;
  const float* xp = x + ((size_t)row * SS + t) * DD + sg * 32 + lkg * 4;
  half8 hv;
#pragma unroll
  for (int j = 0; j < 4; ++j) { hv[j] = (_Float16)xp[j]; hv[4 + j] = (_Float16)xp[16 + j]; }
  *(half8*)(Xh + ((((size_t)t * 16 + sg) * 64 + row) * 4 + lkg) * 8) = hv;
}

// ---- packet layout --------------------------------------------------------
// Packet (producer p, row, s) at uint4 index (p*64 + row)*3 + s:
//   s=0: h[row][16p+0..5] | s=1: h[row][16p+6..11] | s=2: h[row][16p+12..15],0,0
//   dword3 = tag. PRODUCER-CONTIGUOUS: block p's per-step publish is one
//   3072B region (48 whole 64B lines) -> stores coalesce, no partial-line
//   HBM RMW (r7/r8's 3x write amplification + slow visibility).
// Consumer fragment = 8 cols from col0 = 16p + (lkg&1)*8:
//   lkg even reads (s0,s1); lkg odd reads (s1,s2). 16B stores are single-copy
//   atomic at the coherent point (validated r6-r8).

__device__ __forceinline__ void issue_pk(const uint4v* __restrict__ Pb, int p, int s0,
                                         int lrow, uint4v (&P0)[4], uint4v (&P1)[4]) {
#pragma unroll
  for (int mt = 0; mt < 4; ++mt) {
    const uint4v* ap = Pb + ((size_t)(p * 64 + mt * 16 + lrow) * 3 + s0);
    asm volatile("global_load_dwordx4 %0, %2, off sc0 sc1\n\t"
                 "global_load_dwordx4 %1, %2, off offset:16 sc0 sc1"
                 : "=&v"(P0[mt]), "=&v"(P1[mt]) : "v"(ap) : "memory");
  }
}

__device__ __forceinline__ int tags_ok(const uint4v (&P0)[4], const uint4v (&P1)[4],
                                       unsigned want) {
  unsigned bad = 0;
#pragma unroll
  for (int f = 0; f < 4; ++f) bad |= (P0[f][3] ^ want) | (P1[f][3] ^ want);
  return __all(bad == 0);
}

__device__ __forceinline__ void compute_pk(const uint4v (&P0)[4], const uint4v (&P1)[4],
                                           int odd, int kb, const half8 (&bh)[3][4],
                                           const half8 (&b4)[4], f32x4 (&acc)[5][4]) {
#pragma unroll
  for (int mt = 0; mt < 4; ++mt) {
    uint4v fv;
    fv[0] = odd ? P0[mt][1] : P0[mt][0];
    fv[1] = odd ? P0[mt][2] : P0[mt][1];
    fv[2] = odd ? P1[mt][0] : P0[mt][2];
    fv[3] = odd ? P1[mt][1] : P1[mt][0];
    half8 af = __builtin_bit_cast(half8, fv);
    acc[0][mt] = MFMA(af, bh[0][kb], acc[0][mt]);
    acc[1][mt] = MFMA(af, bh[1][kb], acc[1][mt]);
    acc[2][mt] = MFMA(af, bh[2][kb], acc[2][mt]);
    acc[4][mt] = MFMA(af, b4[kb], acc[4][mt]);
  }
}

#define WAITV(lit) do { asm volatile("s_waitcnt vmcnt(" lit ")" ::: "memory"); \
                        __builtin_amdgcn_sched_barrier(0); } while (0)

__global__ __launch_bounds__(512, 2) void rnn_seq(
    const _Float16* __restrict__ Xh, const _Float16* __restrict__ Wp,
    const float* __restrict__ bg, const float* __restrict__ bih,
    const float* __restrict__ bhh, float* __restrict__ out,
    uint4v* __restrict__ Pk) {
  const int blk = blockIdx.x;
  const int tid = threadIdx.x;
  const int w = tid >> 6;              // wave 0..7
  const int lane = tid & 63;
  const int lrow = lane & 15;
  const int lkg = lane >> 4;
  const int odd = lkg & 1;
  const int s0 = lkg & 1;

  __shared__ float Red[4][80][68];               // 87,040 B
  __shared__ alignas(16) _Float16 Hst[64][16];   //  2,048 B
  __shared__ alignas(16) _Float16 Xstage[64 * 512];  // 65,536 B

  const int ej = tid & 15;
  const int rpp = tid >> 4;            // 0..31
  const int ghcol = blk * 16 + ej;
  const float bg_b  = bg[ghcol];
  const float br_b  = bih[ghcol] + bhh[ghcol];
  const float bz_b  = bih[HH + ghcol] + bhh[HH + ghcol];
  const float bin_b = bih[2 * HH + ghcol];
  const float bhn_b = bhh[2 * HH + ghcol];
  float hreg[2] = {0.f, 0.f};

  // batch kb covers h-cols [(w*4+kb)*32 + lkg*8, +8) -> producer p = pbase+kb*2
  const int pbase = w * 8 + (lkg >> 1);

  // register-resident weights (24 half8 = 96 VGPR)
  half8 bx[3][2], b3[2], bh[3][4], b4[4];
#pragma unroll
  for (int tt = 0; tt < 3; ++tt)
#pragma unroll
    for (int kk = 0; kk < 2; ++kk)
      bx[tt][kk] = *(const half8*)(Wp + (size_t)(blk * 80 + tt * 16 + lrow) * KK + (w * 2 + kk) * 32 + lkg * 8);
#pragma unroll
  for (int kk = 0; kk < 2; ++kk)
    b3[kk] = *(const half8*)(Wp + (size_t)(blk * 80 + 48 + lrow) * KK + (w * 2 + kk) * 32 + lkg * 8);
#pragma unroll
  for (int tt = 0; tt < 3; ++tt)
#pragma unroll
    for (int kk = 0; kk < 4; ++kk)
      bh[tt][kk] = *(const half8*)(Wp + (size_t)(blk * 80 + tt * 16 + lrow) * KK + (16 + w * 4 + kk) * 32 + lkg * 8);
#pragma unroll
  for (int kk = 0; kk < 4; ++kk)
    b4[kk] = *(const half8*)(Wp + (size_t)(blk * 80 + 64 + lrow) * KK + (16 + w * 4 + kk) * 32 + lkg * 8);

  // prefetch Xstage(t=0)
#pragma unroll
  for (int kk = 0; kk < 2; ++kk)
#pragma unroll
    for (int mt = 0; mt < 4; ++mt) {
      const _Float16* gsrc = Xh + ((((size_t)0 * 16 + (w * 2 + kk)) * 64 + (mt * 16 + lrow)) * 4 + lkg) * 8;
      __builtin_amdgcn_global_load_lds(
          (const __attribute__((address_space(1))) void*)gsrc,
          (__attribute__((address_space(3))) void*)(Xstage + (w * 8 + kk * 4 + mt) * 512), 16, 0, 0);
    }
  WAITV("0");

  for (int t = 0; t < SS; ++t) {
    const uint4v* Pb = Pk + (size_t)(t & 1) * PKU4;
    uint4v* Pn = Pk + (size_t)((t + 1) & 1) * PKU4;
    const unsigned want = (unsigned)t;

    f32x4 zz = {0.f, 0.f, 0.f, 0.f};
    f32x4 acc[5][4];
#pragma unroll
    for (int tt = 0; tt < 5; ++tt)
#pragma unroll
      for (int mt = 0; mt < 4; ++mt) acc[tt][mt] = zz;

    // issue A(kb0), B(kb1); RT overlaps x-phase + xpref issue.
    // VMEM queue/wave: [pub:1 (w<4, t>0)][A:8][B:8][xpref:8]
    uint4v A0[4], A1[4], B0[4], B1[4];
    issue_pk(Pb, pbase + 0, s0, lrow, A0, A1);
    issue_pk(Pb, pbase + 2, s0, lrow, B0, B1);

    // ---- x-part from LDS (DS-only; Xstage(t) resident since prev sync2) ----
#pragma unroll
    for (int kk = 0; kk < 2; ++kk) {
      half8 afr[4];
#pragma unroll
      for (int mt = 0; mt < 4; ++mt)
        afr[mt] = *(const half8*)(Xstage + (w * 8 + kk * 4 + mt) * 512 + lane * 8);
#pragma unroll
      for (int mt = 0; mt < 4; ++mt) {
        acc[0][mt] = MFMA(afr[mt], bx[0][kk], acc[0][mt]);
        acc[1][mt] = MFMA(afr[mt], bx[1][kk], acc[1][mt]);
        acc[2][mt] = MFMA(afr[mt], bx[2][kk], acc[2][mt]);
        acc[3][mt] = MFMA(afr[mt], b3[kk], acc[3][mt]);
      }
    }

    // ---- xpref(t+1): issued BEFORE sync1 so it fills the wait window; its
    // 8 loads sit behind A,B in the queue (uniform vmcnt math below).
    {
      const int tn = (t + 1 < SS) ? t + 1 : t;
      asm volatile("s_waitcnt lgkmcnt(0)" ::: "memory");  // x ds_reads done (WAR)
      __builtin_amdgcn_sched_barrier(0);
#pragma unroll
      for (int kk = 0; kk < 2; ++kk)
#pragma unroll
        for (int mt = 0; mt < 4; ++mt) {
          const _Float16* gsrc = Xh + ((((size_t)tn * 16 + (w * 2 + kk)) * 64 + (mt * 16 + lrow)) * 4 + lkg) * 8;
          __builtin_amdgcn_global_load_lds(
              (const __attribute__((address_space(1))) void*)gsrc,
              (__attribute__((address_space(3))) void*)(Xstage + (w * 8 + kk * 4 + mt) * 512), 16, 0, 0);
        }
    }

    // ---- sync1: A,B done when <=8 outstanding (xpref). pub (w<4) retired too:
    // queue 25 (or 24) ops, vmcnt(8) retires pub+A+B exactly.
    WAITV("8");
    if (!(tags_ok(A0, A1, want) && tags_ok(B0, B1, want))) {
      for (;;) {
        int okA = tags_ok(A0, A1, want);
        int okB = tags_ok(B0, B1, want);
        if (okA && okB) break;
        if (!okA) issue_pk(Pb, pbase + 0, s0, lrow, A0, A1);
        if (!okB) issue_pk(Pb, pbase + 2, s0, lrow, B0, B1);
        WAITV("0");
      }
    }
    compute_pk(A0, A1, odd, 0, bh, b4, acc);
    issue_pk(Pb, pbase + 4, s0, lrow, A0, A1);   // C -> A regs
    compute_pk(B0, B1, odd, 1, bh, b4, acc);
    issue_pk(Pb, pbase + 6, s0, lrow, B0, B1);   // D -> B regs

    // ---- sync2: drain C,D (and any leftover xpref) ----
    WAITV("0");
    if (!(tags_ok(A0, A1, want) && tags_ok(B0, B1, want))) {
      for (;;) {
        int okC = tags_ok(A0, A1, want);
        int okD = tags_ok(B0, B1, want);
        if (okC && okD) break;
        if (!okC) issue_pk(Pb, pbase + 4, s0, lrow, A0, A1);
        if (!okD) issue_pk(Pb, pbase + 6, s0, lrow, B0, B1);
        WAITV("0");
      }
    }
    compute_pk(A0, A1, odd, 2, bh, b4, acc);
    compute_pk(B0, B1, odd, 3, bh, b4, acc);

    // ---- cross-wave reduction (8 partials -> 4) ----
    if (w >= 4) {
#pragma unroll
      for (int tt = 0; tt < 5; ++tt)
#pragma unroll
        for (int mt = 0; mt < 4; ++mt)
          *(f32x4*)&Red[w - 4][tt * 16 + lrow][mt * 16 + lkg * 4] = acc[tt][mt];
    }
    __syncthreads();
    if (w < 4) {
#pragma unroll
      for (int tt = 0; tt < 5; ++tt)
#pragma unroll
        for (int mt = 0; mt < 4; ++mt) {
          f32x4* p = (f32x4*)&Red[w][tt * 16 + lrow][mt * 16 + lkg * 4];
          *p = *p + acc[tt][mt];
        }
    }
    __syncthreads();

    // ---- epilogue: all 512 threads, 2 rows x 1 col ----
    {
      f32x2 s[5];
#pragma unroll
      for (int g = 0; g < 5; ++g) {
        f32x2 a = *(const f32x2*)&Red[0][g * 16 + ej][rpp * 2];
#pragma unroll
        for (int ww = 1; ww < 4; ++ww)
          a = a + *(const f32x2*)&Red[ww][g * 16 + ej][rpp * 2];
        s[g] = a;
      }
#pragma unroll
      for (int r = 0; r < 2; ++r) {
        float g_ = 1.f / (1.f + __expf(-(s[0][r] + bg_b)));
        float r_ = 1.f / (1.f + __expf(-(s[1][r] + br_b)));
        float z_ = 1.f / (1.f + __expf(-(s[2][r] + bz_b)));
        float n_ = tanhf(s[3][r] + bin_b + r_ * (s[4][r] + bhn_b));
        float h = g_ * ((1.f - z_) * n_ + z_ * hreg[r]);
        hreg[r] = h;
        int row = rpp * 2 + r;
        if (t == SS - 1) out[row * HH + ghcol] = h;
        else             Hst[row][ej] = (_Float16)h;
      }
    }

    // ---- publish: fire-and-forget tagged packets into OUR contiguous 3KB
    // region (48 whole lines -> clean coalesced writeback, fast visibility).
    if (t < SS - 1) {
      __syncthreads();                 // Hst complete (also fences Red reads)
      if (tid < 256) {
        const int prow = tid >> 2, ps = tid & 3;
        if (ps < 3) {                  // 192 stores: rows x 3 packets
          uint4v lo = *(const uint4v*)&Hst[prow][0];
          uint4v hi = *(const uint4v*)&Hst[prow][8];
          uint4v pk = {0u, 0u, 0u, (unsigned)(t + 1)};
          if (ps == 0)      { pk[0] = lo[0]; pk[1] = lo[1]; pk[2] = lo[2]; }
          else if (ps == 1) { pk[0] = lo[3]; pk[1] = hi[0]; pk[2] = hi[1]; }
          else              { pk[0] = hi[2]; pk[1] = hi[3]; }
          uint4v* dst = Pn + ((size_t)(blk * 64 + prow) * 3 + ps);
          asm volatile("global_store_dwordx4 %0, %1, off sc0 sc1" :: "v"(dst), "v"(pk) : "memory");
        }
      }
    }
  }
}

extern "C" void kernel_launch(void* const* d_in, const int* in_sizes, int n_in,
                              void* d_out, int out_size, void* d_ws, size_t ws_size,
                              hipStream_t stream) {
  const float* x   = (const float*)d_in[0];
  const float* Wg  = (const float*)d_in[1];
  const float* bg  = (const float*)d_in[2];
  const float* Wih = (const float*)d_in[3];
  const float* bih = (const float*)d_in[4];
  const float* Whh = (const float*)d_in[5];
  const float* bhh = (const float*)d_in[6];
  // d_in[7..10] (Wa, ba, Ws, bs) are mathematically dead: softmax over size-1 axis == 1
  float* out = (float*)d_out;

  char* ws = (char*)d_ws;
  _Float16* Wp = (_Float16*)ws;                        // 15,728,640 B
  _Float16* Xh = (_Float16*)(ws + 15728640);           // 33,554,432 B
  uint4v*   Pk = (uint4v*)(ws + 15728640 + 33554432);  // 2*196,608 = 393,216 B

  // Clear both parities each launch: tag 0 == valid zero h(0) for t=0; stale
  // tags from a previous replay can never equal want=t>0 after the wipe.
  hipMemsetAsync((void*)Pk, 0, 393216, stream);
  prep_w<<<5120, 256, 0, stream>>>(Wg, Wih, Whh, Wp);
  prep_xh<<<dim3(512, 16), 256, 0, stream>>>(x, Xh);
  rnn_seq<<<64, 512, 0, stream>>>(Xh, Wp, bg, bih, bhh, out, Pk);
}

// Round 10
// 4768.510 us; speedup vs baseline: 2.0745x; 1.2929x over previous
//
#include <hip/hip_runtime.h>

typedef _Float16 half8 __attribute__((ext_vector_type(8)));
typedef float f32x4 __attribute__((ext_vector_type(4)));
typedef float f32x2 __attribute__((ext_vector_type(2)));

#define BB 64
#define SS 512
#define DD 512
#define HH 1024
#define KK 1536
#define NBLK 64

#define MFMA(a, b, c) __builtin_amdgcn_mfma_f32_16x16x32_f16(a, b, c, 0, 0, 0)

// x-region of Wp: fragment permutation; h-region: identity on both operands
// (the shared permutation cancels inside the MFMA dot product).
__device__ __host__ __forceinline__ int kperm(int k) {
  int blk = k >> 5, r = k & 31;
  return (blk << 5) | (((r >> 2) & 3) << 3) | ((r >> 4) << 2) | (r & 3);
}

// Pack weights: Wp[p][k'] fp16, p = b*80 + tile*16 + c  (tile: 0=g,1=r,2=z,3=i_n,4=h_n)
__global__ void prep_w(const float* __restrict__ Wg, const float* __restrict__ Wih,
                       const float* __restrict__ Whh, _Float16* __restrict__ Wp) {
  int p = blockIdx.x;
  int b = p / 80, rem = p % 80, t = rem >> 4, c = rem & 15;
  int j = b * 16 + c;
  for (int pass = 0; pass < 6; ++pass) {
    int k = pass * 256 + threadIdx.x;
    float v;
    if (t == 0)      v = Wg[k * HH + j];
    else if (t == 1) v = (k < DD) ? Wih[k * 3 * HH + j]          : Whh[(k - DD) * 3 * HH + j];
    else if (t == 2) v = (k < DD) ? Wih[k * 3 * HH + HH + j]     : Whh[(k - DD) * 3 * HH + HH + j];
    else if (t == 3) v = (k < DD) ? Wih[k * 3 * HH + 2 * HH + j] : 0.f;
    else             v = (k < DD) ? 0.f : Whh[(k - DD) * 3 * HH + 2 * HH + j];
    int pos = (k < DD) ? kperm(k) : k;      // x: kperm'd, h: identity
    Wp[(size_t)p * KK + pos] = (_Float16)v;
  }
}

// Xh[t][sg][row][lkg][8]: fp16 x in fragment-ready order (sg = x k-step 0..15)
__global__ void prep_xh(const float* __restrict__ x, _Float16* __restrict__ Xh) {
  int t = blockIdx.x, sg = blockIdx.y;
  int row = threadIdx.x >> 2, lkg = threadIdx.x & 3;
  const float* xp = x + ((size_t)row * SS + t) * DD + sg * 32 + lkg * 4;
  half8 hv;
#pragma unroll
  for (int j = 0; j < 4; ++j) { hv[j] = (_Float16)xp[j]; hv[4 + j] = (_Float16)xp[16 + j]; }
  *(half8*)(Xh + ((((size_t)t * 16 + sg) * 64 + row) * 4 + lkg) * 8) = hv;
}

#define WAITV(lit) do { asm volatile("s_waitcnt vmcnt(" lit ")" ::: "memory"); \
                        __builtin_amdgcn_sched_barrier(0); } while (0)

__global__ __launch_bounds__(512, 2) void rnn_seq(
    const _Float16* __restrict__ Xh, const _Float16* __restrict__ Wp,
    const float* __restrict__ bg, const float* __restrict__ bih,
    const float* __restrict__ bhh, float* __restrict__ out,
    _Float16* __restrict__ Hbuf, unsigned* __restrict__ flags) {
  const int blk = blockIdx.x;
  const int tid = threadIdx.x;
  const int w = tid >> 6;              // wave 0..7
  const int lane = tid & 63;
  const int lrow = lane & 15;
  const int lkg = lane >> 4;

  __shared__ float Red[4][80][68];               // 87,040 B
  __shared__ alignas(16) _Float16 Hst[64][16];   //  2,048 B
  __shared__ alignas(16) _Float16 Xstage[64 * 512];  // 65,536 B

  const int ej = tid & 15;
  const int rpp = tid >> 4;            // 0..31
  const int ghcol = blk * 16 + ej;
  const float bg_b  = bg[ghcol];
  const float br_b  = bih[ghcol] + bhh[ghcol];
  const float bz_b  = bih[HH + ghcol] + bhh[HH + ghcol];
  const float bin_b = bih[2 * HH + ghcol];
  const float bhn_b = bhh[2 * HH + ghcol];
  float hreg[2] = {0.f, 0.f};

  // wave w consumes h cols [w*128, w*128+128) -> producers 8w .. 8w+7 only
  const int myprod = 8 * w + (lane & 7);

  // register-resident weights (24 half8 = 96 VGPR), r5 layout
  half8 bx[3][2], b3[2], bh[3][4], b4[4];
#pragma unroll
  for (int tt = 0; tt < 3; ++tt)
#pragma unroll
    for (int kk = 0; kk < 2; ++kk)
      bx[tt][kk] = *(const half8*)(Wp + (size_t)(blk * 80 + tt * 16 + lrow) * KK + (w * 2 + kk) * 32 + lkg * 8);
#pragma unroll
  for (int kk = 0; kk < 2; ++kk)
    b3[kk] = *(const half8*)(Wp + (size_t)(blk * 80 + 48 + lrow) * KK + (w * 2 + kk) * 32 + lkg * 8);
#pragma unroll
  for (int tt = 0; tt < 3; ++tt)
#pragma unroll
    for (int kk = 0; kk < 4; ++kk)
      bh[tt][kk] = *(const half8*)(Wp + (size_t)(blk * 80 + tt * 16 + lrow) * KK + (16 + w * 4 + kk) * 32 + lkg * 8);
#pragma unroll
  for (int kk = 0; kk < 4; ++kk)
    b4[kk] = *(const half8*)(Wp + (size_t)(blk * 80 + 64 + lrow) * KK + (16 + w * 4 + kk) * 32 + lkg * 8);

  // prefetch Xstage(t=0)
#pragma unroll
  for (int kk = 0; kk < 2; ++kk)
#pragma unroll
    for (int mt = 0; mt < 4; ++mt) {
      const _Float16* gsrc = Xh + ((((size_t)0 * 16 + (w * 2 + kk)) * 64 + (mt * 16 + lrow)) * 4 + lkg) * 8;
      __builtin_amdgcn_global_load_lds(
          (const __attribute__((address_space(1))) void*)gsrc,
          (__attribute__((address_space(3))) void*)(Xstage + (w * 8 + kk * 4 + mt) * 512), 16, 0, 0);
    }
  WAITV("0");

  for (int t = 0; t < SS; ++t) {
    const _Float16* Hb = Hbuf + (size_t)(t & 1) * (BB * HH);
    _Float16* Hn = Hbuf + (size_t)((t + 1) & 1) * (BB * HH);

    f32x4 zz = {0.f, 0.f, 0.f, 0.f};
    f32x4 acc[5][4];
#pragma unroll
    for (int tt = 0; tt < 5; ++tt)
#pragma unroll
      for (int mt = 0; mt < 4; ++mt) acc[tt][mt] = zz;

    // ---- x ds_reads into registers (Xstage(t) resident via prev drain) ----
    half8 xfr[2][4];
#pragma unroll
    for (int kk = 0; kk < 2; ++kk)
#pragma unroll
      for (int mt = 0; mt < 4; ++mt)
        xfr[kk][mt] = *(const half8*)(Xstage + (w * 8 + kk * 4 + mt) * 512 + lane * 8);
    asm volatile("s_waitcnt lgkmcnt(0)" ::: "memory");   // reads retired (WAR)
    __builtin_amdgcn_sched_barrier(0);

    // ---- xpref(t+1): issued BEFORE the poll; latency hides under the wait
    {
      const int tn = (t + 1 < SS) ? t + 1 : t;
#pragma unroll
      for (int kk = 0; kk < 2; ++kk)
#pragma unroll
        for (int mt = 0; mt < 4; ++mt) {
          const _Float16* gsrc = Xh + ((((size_t)tn * 16 + (w * 2 + kk)) * 64 + (mt * 16 + lrow)) * 4 + lkg) * 8;
          __builtin_amdgcn_global_load_lds(
              (const __attribute__((address_space(1))) void*)gsrc,
              (__attribute__((address_space(3))) void*)(Xstage + (w * 8 + kk * 4 + mt) * 512), 16, 0, 0);
        }
    }

    // ---- per-wave poll: wait ONLY on this wave's 8 producers (fan-in 8,
    // no block-wide barrier -> waves decouple, cascade tail shrinks).
    for (;;) {
      unsigned v = __hip_atomic_load(&flags[myprod], __ATOMIC_RELAXED, __HIP_MEMORY_SCOPE_AGENT);
      if (__all((int)(v >= (unsigned)t))) break;
      __builtin_amdgcn_s_sleep(1);
    }
    __builtin_amdgcn_sched_barrier(0);

    // ---- issue both h batches; x-MFMA below hides their latency ----
    half8 ha[2][4], hb[2][4];
#pragma unroll
    for (int kk = 0; kk < 2; ++kk)
#pragma unroll
      for (int mt = 0; mt < 4; ++mt) {
        const _Float16* hp = Hb + (size_t)(mt * 16 + lrow) * HH + (w * 4 + kk) * 32 + lkg * 8;
        asm volatile("global_load_dwordx4 %0, %1, off sc0 sc1"
                     : "=&v"(ha[kk][mt]) : "v"(hp) : "memory");
      }
#pragma unroll
    for (int kk = 0; kk < 2; ++kk)
#pragma unroll
      for (int mt = 0; mt < 4; ++mt) {
        const _Float16* hp = Hb + (size_t)(mt * 16 + lrow) * HH + (w * 4 + 2 + kk) * 32 + lkg * 8;
        asm volatile("global_load_dwordx4 %0, %1, off sc0 sc1"
                     : "=&v"(hb[kk][mt]) : "v"(hp) : "memory");
      }

    // ---- x-MFMA from registers (overlaps h-load round trip) ----
#pragma unroll
    for (int kk = 0; kk < 2; ++kk)
#pragma unroll
      for (int mt = 0; mt < 4; ++mt) {
        acc[0][mt] = MFMA(xfr[kk][mt], bx[0][kk], acc[0][mt]);
        acc[1][mt] = MFMA(xfr[kk][mt], bx[1][kk], acc[1][mt]);
        acc[2][mt] = MFMA(xfr[kk][mt], bx[2][kk], acc[2][mt]);
        acc[3][mt] = MFMA(xfr[kk][mt], b3[kk], acc[3][mt]);
      }

    // ---- h-MFMA: counted waits (poll's implicit drains cleared the queue;
    // exactly [ha:8][hb:8] outstanding here) ----
    WAITV("8");                          // ha ready, hb in flight
#pragma unroll
    for (int kk = 0; kk < 2; ++kk)
#pragma unroll
      for (int mt = 0; mt < 4; ++mt) {
        acc[0][mt] = MFMA(ha[kk][mt], bh[0][kk], acc[0][mt]);
        acc[1][mt] = MFMA(ha[kk][mt], bh[1][kk], acc[1][mt]);
        acc[2][mt] = MFMA(ha[kk][mt], bh[2][kk], acc[2][mt]);
        acc[4][mt] = MFMA(ha[kk][mt], b4[kk], acc[4][mt]);
      }
    WAITV("0");                          // hb ready
#pragma unroll
    for (int kk = 0; kk < 2; ++kk)
#pragma unroll
      for (int mt = 0; mt < 4; ++mt) {
        acc[0][mt] = MFMA(hb[kk][mt], bh[0][2 + kk], acc[0][mt]);
        acc[1][mt] = MFMA(hb[kk][mt], bh[1][2 + kk], acc[1][mt]);
        acc[2][mt] = MFMA(hb[kk][mt], bh[2][2 + kk], acc[2][mt]);
        acc[4][mt] = MFMA(hb[kk][mt], b4[2 + kk], acc[4][mt]);
      }

    // ---- cross-wave reduction (8 partials -> 4); Red WAR vs prev epilogue
    // is protected by the end-of-step publish barriers ----
    if (w >= 4) {
#pragma unroll
      for (int tt = 0; tt < 5; ++tt)
#pragma unroll
        for (int mt = 0; mt < 4; ++mt)
          *(f32x4*)&Red[w - 4][tt * 16 + lrow][mt * 16 + lkg * 4] = acc[tt][mt];
    }
    __syncthreads();
    if (w < 4) {
#pragma unroll
      for (int tt = 0; tt < 5; ++tt)
#pragma unroll
        for (int mt = 0; mt < 4; ++mt) {
          f32x4* p = (f32x4*)&Red[w][tt * 16 + lrow][mt * 16 + lkg * 4];
          *p = *p + acc[tt][mt];
        }
    }
    __syncthreads();

    // ---- epilogue: all 512 threads, 2 rows x 1 col ----
    {
      f32x2 s[5];
#pragma unroll
      for (int g = 0; g < 5; ++g) {
        f32x2 a = *(const f32x2*)&Red[0][g * 16 + ej][rpp * 2];
#pragma unroll
        for (int ww = 1; ww < 4; ++ww)
          a = a + *(const f32x2*)&Red[ww][g * 16 + ej][rpp * 2];
        s[g] = a;
      }
#pragma unroll
      for (int r = 0; r < 2; ++r) {
        float g_ = 1.f / (1.f + __expf(-(s[0][r] + bg_b)));
        float r_ = 1.f / (1.f + __expf(-(s[1][r] + br_b)));
        float z_ = 1.f / (1.f + __expf(-(s[2][r] + bz_b)));
        float n_ = tanhf(s[3][r] + bin_b + r_ * (s[4][r] + bhn_b));
        float h = g_ * ((1.f - z_) * n_ + z_ * hreg[r]);
        hreg[r] = h;
        int row = rpp * 2 + r;
        if (t == SS - 1) out[row * HH + ghcol] = h;
        else             Hst[row][ej] = (_Float16)h;
      }
    }

    if (t < SS - 1) {
      __syncthreads();                 // Hst complete (orders Red reads too)
      if (tid < 128) {                 // 128 x 16B coalesced stores to MALL
        int row = tid >> 1, hf = tid & 1;
        half8 hv = *(const half8*)&Hst[row][hf * 8];
        _Float16* hp = Hn + (size_t)row * HH + blk * 16 + hf * 8;
        asm volatile("global_store_dwordx4 %0, %1, off sc0 sc1"
                     :: "v"(hp), "v"(hv) : "memory");
      }
      asm volatile("s_waitcnt vmcnt(0)" ::: "memory");  // stores at coherent point
      __syncthreads();                                  // all waves drained
      if (tid == 0)
        __hip_atomic_store(&flags[blk], (unsigned)(t + 1), __ATOMIC_RELAXED, __HIP_MEMORY_SCOPE_AGENT);
    }
  }
}

extern "C" void kernel_launch(void* const* d_in, const int* in_sizes, int n_in,
                              void* d_out, int out_size, void* d_ws, size_t ws_size,
                              hipStream_t stream) {
  const float* x   = (const float*)d_in[0];
  const float* Wg  = (const float*)d_in[1];
  const float* bg  = (const float*)d_in[2];
  const float* Wih = (const float*)d_in[3];
  const float* bih = (const float*)d_in[4];
  const float* Whh = (const float*)d_in[5];
  const float* bhh = (const float*)d_in[6];
  // d_in[7..10] (Wa, ba, Ws, bs) are mathematically dead: softmax over size-1 axis == 1
  float* out = (float*)d_out;

  char* ws = (char*)d_ws;
  _Float16* Wp    = (_Float16*)ws;                        // 15,728,640 B
  _Float16* Xh    = (_Float16*)(ws + 15728640);           // 33,554,432 B
  _Float16* Hbuf  = (_Float16*)(ws + 15728640 + 33554432);        // 262,144 B
  unsigned* flags = (unsigned*)(ws + 15728640 + 33554432 + 262144); // 256 B

  hipMemsetAsync((void*)Hbuf, 0, 262144 + 256, stream);   // h0 = 0, flags = 0
  prep_w<<<5120, 256, 0, stream>>>(Wg, Wih, Whh, Wp);
  prep_xh<<<dim3(512, 16), 256, 0, stream>>>(x, Xh);
  rnn_seq<<<64, 512, 0, stream>>>(Xh, Wp, bg, bih, bhh, out, Hbuf, flags);
}

// Round 12
// 4595.543 us; speedup vs baseline: 2.1526x; 1.0376x over previous
//
#include <hip/hip_runtime.h>

typedef _Float16 half8 __attribute__((ext_vector_type(8)));
typedef float f32x4 __attribute__((ext_vector_type(4)));
typedef float f32x2 __attribute__((ext_vector_type(2)));

#define BB 64
#define SS 512
#define DD 512
#define HH 1024
#define KK 1536
#define NBLK 64

#define MFMA(a, b, c) __builtin_amdgcn_mfma_f32_16x16x32_f16(a, b, c, 0, 0, 0)

// x-region of Wp: fragment permutation; h-region: identity on both operands
// (the shared permutation cancels inside the MFMA dot product).
__device__ __host__ __forceinline__ int kperm(int k) {
  int blk = k >> 5, r = k & 31;
  return (blk << 5) | (((r >> 2) & 3) << 3) | ((r >> 4) << 2) | (r & 3);
}

// Pack weights: Wp[p][k'] fp16, p = b*80 + tile*16 + c  (tile: 0=g,1=r,2=z,3=i_n,4=h_n)
__global__ void prep_w(const float* __restrict__ Wg, const float* __restrict__ Wih,
                       const float* __restrict__ Whh, _Float16* __restrict__ Wp) {
  int p = blockIdx.x;
  int b = p / 80, rem = p % 80, t = rem >> 4, c = rem & 15;
  int j = b * 16 + c;
  for (int pass = 0; pass < 6; ++pass) {
    int k = pass * 256 + threadIdx.x;
    float v;
    if (t == 0)      v = Wg[k * HH + j];
    else if (t == 1) v = (k < DD) ? Wih[k * 3 * HH + j]          : Whh[(k - DD) * 3 * HH + j];
    else if (t == 2) v = (k < DD) ? Wih[k * 3 * HH + HH + j]     : Whh[(k - DD) * 3 * HH + HH + j];
    else if (t == 3) v = (k < DD) ? Wih[k * 3 * HH + 2 * HH + j] : 0.f;
    else             v = (k < DD) ? 0.f : Whh[(k - DD) * 3 * HH + 2 * HH + j];
    int pos = (k < DD) ? kperm(k) : k;      // x: kperm'd, h: identity
    Wp[(size_t)p * KK + pos] = (_Float16)v;
  }
}

// Xh[t][sg][row][lkg][8]: fp16 x in fragment-ready order (sg = x k-step 0..15)
__global__ void prep_xh(const float* __restrict__ x, _Float16* __restrict__ Xh) {
  int t = blockIdx.x, sg = blockIdx.y;
  int row = threadIdx.x >> 2, lkg = threadIdx.x & 3;
  const float* xp = x + ((size_t)row * SS + t) * DD + sg * 32 + lkg * 4;
  half8 hv;
#pragma unroll
  for (int j = 0; j < 4; ++j) { hv[j] = (_Float16)xp[j]; hv[4 + j] = (_Float16)xp[16 + j]; }
  *(half8*)(Xh + ((((size_t)t * 16 + sg) * 64 + row) * 4 + lkg) * 8) = hv;
}

#define WAITV(lit) do { asm volatile("s_waitcnt vmcnt(" lit ")" ::: "memory"); \
                        __builtin_amdgcn_sched_barrier(0); } while (0)

__global__ __launch_bounds__(512, 2) void rnn_seq(
    const _Float16* __restrict__ Xh, const _Float16* __restrict__ Wp,
    const float* __restrict__ bg, const float* __restrict__ bih,
    const float* __restrict__ bhh, float* __restrict__ out,
    _Float16* __restrict__ Hbuf, unsigned* __restrict__ flags) {
  const int blk = blockIdx.x;
  const int tid = threadIdx.x;
  const int w = tid >> 6;              // wave 0..7
  const int lane = tid & 63;
  const int lrow = lane & 15;
  const int lkg = lane >> 4;

  __shared__ float Red[4][80][68];               // 87,040 B
  __shared__ alignas(16) _Float16 Hst[64][16];   //  2,048 B
  __shared__ alignas(16) _Float16 Xstage[64 * 512];  // 65,536 B

  const int ej = tid & 15;
  const int rpp = tid >> 4;            // 0..31
  const int ghcol = blk * 16 + ej;
  const float bg_b  = bg[ghcol];
  const float br_b  = bih[ghcol] + bhh[ghcol];
  const float bz_b  = bih[HH + ghcol] + bhh[HH + ghcol];
  const float bin_b = bih[2 * HH + ghcol];
  const float bhn_b = bhh[2 * HH + ghcol];
  float hreg[2] = {0.f, 0.f};

  // wave w consumes h cols [w*128, w*128+128) -> producers 8w .. 8w+7 only
  const int myprod = 8 * w + (lane & 7);

  // register-resident weights (24 half8 = 96 VGPR), r5 layout
  half8 bx[3][2], b3[2], bh[3][4], b4[4];
#pragma unroll
  for (int tt = 0; tt < 3; ++tt)
#pragma unroll
    for (int kk = 0; kk < 2; ++kk)
      bx[tt][kk] = *(const half8*)(Wp + (size_t)(blk * 80 + tt * 16 + lrow) * KK + (w * 2 + kk) * 32 + lkg * 8);
#pragma unroll
  for (int kk = 0; kk < 2; ++kk)
    b3[kk] = *(const half8*)(Wp + (size_t)(blk * 80 + 48 + lrow) * KK + (w * 2 + kk) * 32 + lkg * 8);
#pragma unroll
  for (int tt = 0; tt < 3; ++tt)
#pragma unroll
    for (int kk = 0; kk < 4; ++kk)
      bh[tt][kk] = *(const half8*)(Wp + (size_t)(blk * 80 + tt * 16 + lrow) * KK + (16 + w * 4 + kk) * 32 + lkg * 8);
#pragma unroll
  for (int kk = 0; kk < 4; ++kk)
    b4[kk] = *(const half8*)(Wp + (size_t)(blk * 80 + 64 + lrow) * KK + (16 + w * 4 + kk) * 32 + lkg * 8);

  // prefetch Xstage(t=0)
#pragma unroll
  for (int kk = 0; kk < 2; ++kk)
#pragma unroll
    for (int mt = 0; mt < 4; ++mt) {
      const _Float16* gsrc = Xh + ((((size_t)0 * 16 + (w * 2 + kk)) * 64 + (mt * 16 + lrow)) * 4 + lkg) * 8;
      __builtin_amdgcn_global_load_lds(
          (const __attribute__((address_space(1))) void*)gsrc,
          (__attribute__((address_space(3))) void*)(Xstage + (w * 8 + kk * 4 + mt) * 512), 16, 0, 0);
    }
  WAITV("0");

  for (int t = 0; t < SS; ++t) {
    const _Float16* Hb = Hbuf + (size_t)(t & 1) * (BB * HH);
    _Float16* Hn = Hbuf + (size_t)((t + 1) & 1) * (BB * HH);

    f32x4 zz = {0.f, 0.f, 0.f, 0.f};
    f32x4 acc[5][4];
#pragma unroll
    for (int tt = 0; tt < 5; ++tt)
#pragma unroll
      for (int mt = 0; mt < 4; ++mt) acc[tt][mt] = zz;

    // ---- x ds_reads into registers (Xstage(t) resident via prev drain) ----
    half8 xfr[2][4];
#pragma unroll
    for (int kk = 0; kk < 2; ++kk)
#pragma unroll
      for (int mt = 0; mt < 4; ++mt)
        xfr[kk][mt] = *(const half8*)(Xstage + (w * 8 + kk * 4 + mt) * 512 + lane * 8);
    asm volatile("s_waitcnt lgkmcnt(0)" ::: "memory");   // reads retired (WAR)
    __builtin_amdgcn_sched_barrier(0);

    // ---- xpref(t+1): issued BEFORE the poll; latency hides under the wait
    {
      const int tn = (t + 1 < SS) ? t + 1 : t;
#pragma unroll
      for (int kk = 0; kk < 2; ++kk)
#pragma unroll
        for (int mt = 0; mt < 4; ++mt) {
          const _Float16* gsrc = Xh + ((((size_t)tn * 16 + (w * 2 + kk)) * 64 + (mt * 16 + lrow)) * 4 + lkg) * 8;
          __builtin_amdgcn_global_load_lds(
              (const __attribute__((address_space(1))) void*)gsrc,
              (__attribute__((address_space(3))) void*)(Xstage + (w * 8 + kk * 4 + mt) * 512), 16, 0, 0);
        }
    }

    // ---- per-wave poll: wait ONLY on this wave's 8 producers (fan-in 8);
    // poll-load retirement also drains xpref -> queue empty at ha issue.
    for (;;) {
      unsigned v = __hip_atomic_load(&flags[myprod], __ATOMIC_RELAXED, __HIP_MEMORY_SCOPE_AGENT);
      if (__all((int)(v >= (unsigned)t))) break;
      __builtin_amdgcn_s_sleep(1);
    }
    __builtin_amdgcn_sched_barrier(0);

    // ---- issue both h batches; x-MFMA below hides their latency ----
    half8 ha[2][4], hb[2][4];
#pragma unroll
    for (int kk = 0; kk < 2; ++kk)
#pragma unroll
      for (int mt = 0; mt < 4; ++mt) {
        const _Float16* hp = Hb + (size_t)(mt * 16 + lrow) * HH + (w * 4 + kk) * 32 + lkg * 8;
        asm volatile("global_load_dwordx4 %0, %1, off sc0 sc1"
                     : "=&v"(ha[kk][mt]) : "v"(hp) : "memory");
      }
#pragma unroll
    for (int kk = 0; kk < 2; ++kk)
#pragma unroll
      for (int mt = 0; mt < 4; ++mt) {
        const _Float16* hp = Hb + (size_t)(mt * 16 + lrow) * HH + (w * 4 + 2 + kk) * 32 + lkg * 8;
        asm volatile("global_load_dwordx4 %0, %1, off sc0 sc1"
                     : "=&v"(hb[kk][mt]) : "v"(hp) : "memory");
      }

    // ---- x-MFMA from registers (overlaps h-load round trip) ----
#pragma unroll
    for (int kk = 0; kk < 2; ++kk)
#pragma unroll
      for (int mt = 0; mt < 4; ++mt) {
        acc[0][mt] = MFMA(xfr[kk][mt], bx[0][kk], acc[0][mt]);
        acc[1][mt] = MFMA(xfr[kk][mt], bx[1][kk], acc[1][mt]);
        acc[2][mt] = MFMA(xfr[kk][mt], bx[2][kk], acc[2][mt]);
        acc[3][mt] = MFMA(xfr[kk][mt], b3[kk], acc[3][mt]);
      }

    // ---- h-MFMA: counted waits (queue exactly [ha:8][hb:8] here) ----
    WAITV("8");                          // ha ready, hb in flight
#pragma unroll
    for (int kk = 0; kk < 2; ++kk)
#pragma unroll
      for (int mt = 0; mt < 4; ++mt) {
        acc[0][mt] = MFMA(ha[kk][mt], bh[0][kk], acc[0][mt]);
        acc[1][mt] = MFMA(ha[kk][mt], bh[1][kk], acc[1][mt]);
        acc[2][mt] = MFMA(ha[kk][mt], bh[2][kk], acc[2][mt]);
        acc[4][mt] = MFMA(ha[kk][mt], b4[kk], acc[4][mt]);
      }
    WAITV("0");                          // hb ready
#pragma unroll
    for (int kk = 0; kk < 2; ++kk)
#pragma unroll
      for (int mt = 0; mt < 4; ++mt) {
        acc[0][mt] = MFMA(hb[kk][mt], bh[0][2 + kk], acc[0][mt]);
        acc[1][mt] = MFMA(hb[kk][mt], bh[1][2 + kk], acc[1][mt]);
        acc[2][mt] = MFMA(hb[kk][mt], bh[2][2 + kk], acc[2][mt]);
        acc[4][mt] = MFMA(hb[kk][mt], b4[2 + kk], acc[4][mt]);
      }

    // ---- cross-wave reduction (8 partials -> 4) ----
    if (w >= 4) {
#pragma unroll
      for (int tt = 0; tt < 5; ++tt)
#pragma unroll
        for (int mt = 0; mt < 4; ++mt)
          *(f32x4*)&Red[w - 4][tt * 16 + lrow][mt * 16 + lkg * 4] = acc[tt][mt];
    }
    __syncthreads();
    if (w < 4) {
#pragma unroll
      for (int tt = 0; tt < 5; ++tt)
#pragma unroll
        for (int mt = 0; mt < 4; ++mt) {
          f32x4* p = (f32x4*)&Red[w][tt * 16 + lrow][mt * 16 + lkg * 4];
          *p = *p + acc[tt][mt];
        }
    }
    __syncthreads();

    // ---- epilogue: all 512 threads, 2 rows x 1 col ----
    {
      f32x2 s[5];
#pragma unroll
      for (int g = 0; g < 5; ++g) {
        f32x2 a = *(const f32x2*)&Red[0][g * 16 + ej][rpp * 2];
#pragma unroll
        for (int ww = 1; ww < 4; ++ww)
          a = a + *(const f32x2*)&Red[ww][g * 16 + ej][rpp * 2];
        s[g] = a;
      }
#pragma unroll
      for (int r = 0; r < 2; ++r) {
        float g_ = 1.f / (1.f + __expf(-(s[0][r] + bg_b)));
        float r_ = 1.f / (1.f + __expf(-(s[1][r] + br_b)));
        float z_ = 1.f / (1.f + __expf(-(s[2][r] + bz_b)));
        float n_ = tanhf(s[3][r] + bin_b + r_ * (s[4][r] + bhn_b));
        float h = g_ * ((1.f - z_) * n_ + z_ * hreg[r]);
        hreg[r] = h;
        int row = rpp * 2 + r;
        if (t == SS - 1) out[row * HH + ghcol] = h;
        else             Hst[row][ej] = (_Float16)h;
      }
    }

    // ---- publish: wave 0 ONLY (single change vs r10). Last barrier of the
    // step; waves 1-7 race ahead into x(t+1)/xpref/poll while wave 0 does
    // stores+drain+flag. Hazards: Hst WAR safe (wave 0's reads precede its
    // arrival at t+1's reduce barriers, which gate the next epilogue); Red
    // WAR safe (epilogue reads precede this barrier, next writes follow it);
    // parity backpressure unchanged (publish barrier orders all 8 waves'
    // polls -- covering all 64 producers -- before these stores).
    if (t < SS - 1) {
      __syncthreads();                 // Hst complete
      if (w == 0) {
        half8 hv0 = *(const half8*)&Hst[lane][0];
        half8 hv1 = *(const half8*)&Hst[lane][8];
        _Float16* hp = Hn + (size_t)lane * HH + blk * 16;
        asm volatile("global_store_dwordx4 %0, %1, off sc0 sc1"
                     :: "v"(hp), "v"(hv0) : "memory");
        asm volatile("global_store_dwordx4 %0, %1, off offset:16 sc0 sc1"
                     :: "v"(hp), "v"(hv1) : "memory");
        asm volatile("s_waitcnt vmcnt(0)" ::: "memory");  // wave 0's stores only
        __builtin_amdgcn_sched_barrier(0);
        if (lane == 0)
          __hip_atomic_store(&flags[blk], (unsigned)(t + 1), __ATOMIC_RELAXED, __HIP_MEMORY_SCOPE_AGENT);
      }
    }
  }
}

extern "C" void kernel_launch(void* const* d_in, const int* in_sizes, int n_in,
                              void* d_out, int out_size, void* d_ws, size_t ws_size,
                              hipStream_t stream) {
  const float* x   = (const float*)d_in[0];
  const float* Wg  = (const float*)d_in[1];
  const float* bg  = (const float*)d_in[2];
  const float* Wih = (const float*)d_in[3];
  const float* bih = (const float*)d_in[4];
  const float* Whh = (const float*)d_in[5];
  const float* bhh = (const float*)d_in[6];
  // d_in[7..10] (Wa, ba, Ws, bs) are mathematically dead: softmax over size-1 axis == 1
  float* out = (float*)d_out;

  char* ws = (char*)d_ws;
  _Float16* Wp    = (_Float16*)ws;                        // 15,728,640 B
  _Float16* Xh    = (_Float16*)(ws + 15728640);           // 33,554,432 B
  _Float16* Hbuf  = (_Float16*)(ws + 15728640 + 33554432);        // 262,144 B
  unsigned* flags = (unsigned*)(ws + 15728640 + 33554432 + 262144); // 256 B

  hipMemsetAsync((void*)Hbuf, 0, 262144 + 256, stream);   // h0 = 0, flags = 0
  prep_w<<<5120, 256, 0, stream>>>(Wg, Wih, Whh, Wp);
  prep_xh<<<dim3(512, 16), 256, 0, stream>>>(x, Xh);
  rnn_seq<<<64, 512, 0, stream>>>(Xh, Wp, bg, bih, bhh, out, Hbuf, flags);
}